// Round 1
// baseline (132.423 us; speedup 1.0000x reference)
//
#include <hip/hip_runtime.h>
#include <hip/hip_bf16.h>
#include <stdint.h>

#define M_DIM 2048
#define N_DIM 4096
#define K_DIM 4096

typedef __attribute__((ext_vector_type(8))) __bf16 bf16x8;
typedef __attribute__((ext_vector_type(4))) float f32x4;

__device__ __constant__ float NF4_TAB[16] = {
    -1.0f, -0.6961928009986877f, -0.5250730514526367f, -0.39491748809814453f,
    -0.28444138169288635f, -0.18477343022823334f, -0.09105003625154495f, 0.0f,
    0.07958029955625534f, 0.16093020141124725f, 0.24611230194568634f,
    0.33791524171829224f, 0.44070982933044434f, 0.5626170039176941f,
    0.7229568362236023f, 1.0f};

// fp32 -> bf16 round-to-nearest-even
__device__ inline unsigned short f2b(float f) {
  union { float f; uint32_t u; } v; v.f = f;
  uint32_t u = v.u;
  return (unsigned short)((u + 0x7fffu + ((u >> 16) & 1u)) >> 16);
}

// ---------------- K1: input fp32 -> bf16 ----------------
__global__ void k_cvt(const float4* __restrict__ in, ushort4* __restrict__ out, int n) {
  int i = blockIdx.x * 256 + threadIdx.x;
  if (i < n) {
    float4 v = in[i];
    ushort4 o;
    o.x = f2b(v.x); o.y = f2b(v.y); o.z = f2b(v.z); o.w = f2b(v.w);
    out[i] = o;
  }
}

// ---------------- K2: fused NF4 dequant + LoRA fold -> bf16 W (N x K) ----------
// One block builds a 64(n) x 64(k) tile of W_eff.
// delta[n][k] = sum_r lora_B[n][r] * lora_A[r][k]  (r = 0..63)
__global__ void __launch_bounds__(256) k_build_w(
    const int* __restrict__ qw, const float* __restrict__ am,
    const float* __restrict__ lA, const float* __restrict__ lB,
    unsigned short* __restrict__ W) {
  __shared__ float As[64][68];   // lora_A[r][k_local], padded (272B rows, 16B aligned)
  __shared__ float BsT[64][68];  // lora_B^T: [r][n_local]
  __shared__ float tab[16];
  const int t = threadIdx.x;
  const int bk = blockIdx.x & 63;   // k-tile (K/64 = 64)
  const int bn = blockIdx.x >> 6;   // n-tile (N/64 = 64)
  const int n0 = bn << 6, k0 = bk << 6;
  if (t < 16) tab[t] = NF4_TAB[t];
#pragma unroll
  for (int i = 0; i < 16; ++i) {
    int idx = i * 256 + t;
    int p = idx >> 6, q = idx & 63;                 // consecutive t -> consecutive q (coalesced)
    As[p][q]  = lA[(size_t)p * K_DIM + k0 + q];     // r=p, k=q
    BsT[q][p] = lB[(size_t)(n0 + p) * 64 + q];      // n=p, r=q
  }
  __syncthreads();
  const int tx = t & 15, ty = t >> 4;               // thread owns 4n x 4k
  float acc[4][4] = {};
#pragma unroll 8
  for (int r = 0; r < 64; ++r) {
    float4 av = *(const float4*)&As[r][tx * 4];
    float4 bv = *(const float4*)&BsT[r][ty * 4];
    float aa[4] = {av.x, av.y, av.z, av.w};
    float bb[4] = {bv.x, bv.y, bv.z, bv.w};
#pragma unroll
    for (int i = 0; i < 4; ++i)
#pragma unroll
      for (int j = 0; j < 4; ++j) acc[i][j] += bb[i] * aa[j];
  }
#pragma unroll
  for (int i = 0; i < 4; ++i) {
    int row = n0 + ty * 4 + i;
    float amv = am[row * 64 + bk];                  // (row*4096 + k0)/64
    // byte index = (row*4096 + k)/2 ; 2 bytes cover the thread's 4 cols
    int2 q2 = *(const int2*)&qw[(size_t)row * 2048 + (k0 >> 1) + tx * 2];
    float w0 = tab[q2.x & 15]        * amv + acc[i][0];  // col 4tx   (low nib)
    float w1 = tab[(q2.x >> 4) & 15] * amv + acc[i][1];  // col 4tx+1 (high nib)
    float w2 = tab[q2.y & 15]        * amv + acc[i][2];
    float w3 = tab[(q2.y >> 4) & 15] * amv + acc[i][3];
    ushort4 o; o.x = f2b(w0); o.y = f2b(w1); o.z = f2b(w2); o.w = f2b(w3);
    *(ushort4*)&W[(size_t)row * K_DIM + k0 + tx * 4] = o;
  }
}

// ---------------- K3: bf16 GEMM, C[m][n] = sum_k A[m][k]*B[n][k] ----------------
// 128x128 tile, BK=64, 4 waves (each 64x64 output), global_load_lds staging with
// pre-swizzled global source (rule #21), XOR-swizzled ds_read_b128 frag reads.
#define BM 128
#define BN 128
#define BK 64

__global__ void __launch_bounds__(256) k_gemm(const unsigned short* __restrict__ A,
                                              const unsigned short* __restrict__ B,
                                              float* __restrict__ C) {
  __shared__ unsigned short As[BM * BK];  // [row][k], 128B per row (8 x 16B slots)
  __shared__ unsigned short Bs[BN * BK];
  const int tid = threadIdx.x;
  const int lane = tid & 63;
  const int wid = tid >> 6;               // 0..3
  const int bm = blockIdx.x & 15;         // M/128 = 16
  const int bn = blockIdx.x >> 4;         // N/128 = 32
  const int wr = wid >> 1, wc = wid & 1;  // 2x2 waves, each 64x64

  const size_t arow0 = (size_t)bm * BM;
  const size_t brow0 = (size_t)bn * BN;

  // staging: lane l writes LDS chunkbase + l*16 (hardware-linear). We want
  // LDS[row][slot] = G[row][slot ^ (row&7)], so lane fetches swizzled source slot.
  const int srow = lane >> 3;                       // row within 8-row chunk
  const int sslot = (lane & 7) ^ (srow & 7);        // pre-swizzled 16B slot
  const char* Ab = (const char*)A;
  const char* Bb = (const char*)B;

  const int lr = lane & 15;   // fragment row (A) / col (B)
  const int lk = lane >> 4;   // k-group 0..3 (8 elems each)

  f32x4 acc[4][4] = {};

  for (int kt = 0; kt < K_DIM / BK; ++kt) {
    __syncthreads();  // previous tile's reads complete before overwrite
#pragma unroll
    for (int i = 0; i < 4; ++i) {
      int crow = wid * 32 + i * 8;  // 8-row chunk this instruction fills
      const char* ga = Ab + ((arow0 + crow + srow) * K_DIM + (size_t)kt * BK) * 2 + sslot * 16;
      __builtin_amdgcn_global_load_lds(
          (const __attribute__((address_space(1))) uint32_t*)ga,
          (__attribute__((address_space(3))) uint32_t*)&As[crow * BK], 16, 0, 0);
      const char* gb = Bb + ((brow0 + crow + srow) * K_DIM + (size_t)kt * BK) * 2 + sslot * 16;
      __builtin_amdgcn_global_load_lds(
          (const __attribute__((address_space(1))) uint32_t*)gb,
          (__attribute__((address_space(3))) uint32_t*)&Bs[crow * BK], 16, 0, 0);
    }
    __syncthreads();  // compiler emits s_waitcnt vmcnt(0) before this barrier
#pragma unroll
    for (int kk = 0; kk < 2; ++kk) {
      bf16x8 af[4], bfr[4];
#pragma unroll
      for (int mi = 0; mi < 4; ++mi) {
        int row = wr * 64 + mi * 16 + lr;
        int slot = (kk * 4 + lk) ^ (row & 7);
        af[mi] = *(const bf16x8*)&As[row * BK + slot * 8];
      }
#pragma unroll
      for (int ni = 0; ni < 4; ++ni) {
        int row = wc * 64 + ni * 16 + lr;
        int slot = (kk * 4 + lk) ^ (row & 7);
        bfr[ni] = *(const bf16x8*)&Bs[row * BK + slot * 8];
      }
#pragma unroll
      for (int mi = 0; mi < 4; ++mi)
#pragma unroll
        for (int ni = 0; ni < 4; ++ni)
          acc[mi][ni] = __builtin_amdgcn_mfma_f32_16x16x32_bf16(af[mi], bfr[ni],
                                                                acc[mi][ni], 0, 0, 0);
    }
  }

  // epilogue: C/D layout col = lane&15, row = (lane>>4)*4 + reg (m89/m91 verified)
  float* Cb = C + (arow0 + (size_t)wr * 64) * N_DIM + brow0 + wc * 64;
#pragma unroll
  for (int mi = 0; mi < 4; ++mi)
#pragma unroll
    for (int ni = 0; ni < 4; ++ni)
#pragma unroll
      for (int r = 0; r < 4; ++r)
        Cb[(size_t)(mi * 16 + lk * 4 + r) * N_DIM + ni * 16 + lr] = acc[mi][ni][r];
}

extern "C" void kernel_launch(void* const* d_in, const int* in_sizes, int n_in,
                              void* d_out, int out_size, void* d_ws, size_t ws_size,
                              hipStream_t stream) {
  const float* input  = (const float*)d_in[0];
  const int* qweight  = (const int*)d_in[1];
  const float* absmax = (const float*)d_in[2];
  const float* lora_A = (const float*)d_in[3];
  const float* lora_B = (const float*)d_in[4];
  float* out = (float*)d_out;

  unsigned short* A16 = (unsigned short*)d_ws;             // 2048*4096 bf16 = 16.8 MB
  unsigned short* B16 = A16 + (size_t)M_DIM * K_DIM;       // 4096*4096 bf16 = 33.6 MB

  // K1: input -> bf16
  int n4 = M_DIM * K_DIM / 4;
  k_cvt<<<n4 / 256, 256, 0, stream>>>((const float4*)input, (ushort4*)A16, n4);
  // K2: W_eff = dequant(qweight, absmax) + lora_B @ lora_A   (bf16, N x K)
  k_build_w<<<(N_DIM / 64) * (K_DIM / 64), 256, 0, stream>>>(qweight, absmax, lora_A,
                                                             lora_B, B16);
  // K3: C = A @ W_eff^T
  k_gemm<<<(M_DIM / BM) * (N_DIM / BN), 256, 0, stream>>>(A16, B16, out);
}

// Round 2
// 117.394 us; speedup vs baseline: 1.1280x; 1.1280x over previous
//
#include <hip/hip_runtime.h>
#include <hip/hip_bf16.h>
#include <stdint.h>

#define M_DIM 2048
#define N_DIM 4096
#define K_DIM 4096

typedef __attribute__((ext_vector_type(8))) __bf16 bf16x8;
typedef __attribute__((ext_vector_type(4))) float f32x4;

__device__ __constant__ float NF4_TAB[16] = {
    -1.0f, -0.6961928009986877f, -0.5250730514526367f, -0.39491748809814453f,
    -0.28444138169288635f, -0.18477343022823334f, -0.09105003625154495f, 0.0f,
    0.07958029955625534f, 0.16093020141124725f, 0.24611230194568634f,
    0.33791524171829224f, 0.44070982933044434f, 0.5626170039176941f,
    0.7229568362236023f, 1.0f};

// fp32 -> bf16 round-to-nearest-even
__device__ inline unsigned short f2b(float f) {
  union { float f; uint32_t u; } v; v.f = f;
  uint32_t u = v.u;
  return (unsigned short)((u + 0x7fffu + ((u >> 16) & 1u)) >> 16);
}

// ---------------- K1: input fp32 -> bf16 ----------------
__global__ void k_cvt(const float4* __restrict__ in, ushort4* __restrict__ out, int n) {
  int i = blockIdx.x * 256 + threadIdx.x;
  if (i < n) {
    float4 v = in[i];
    ushort4 o;
    o.x = f2b(v.x); o.y = f2b(v.y); o.z = f2b(v.z); o.w = f2b(v.w);
    out[i] = o;
  }
}

// ---------------- K2: fused NF4 dequant + LoRA fold -> bf16 W (N x K) ----------
__global__ void __launch_bounds__(256) k_build_w(
    const int* __restrict__ qw, const float* __restrict__ am,
    const float* __restrict__ lA, const float* __restrict__ lB,
    unsigned short* __restrict__ W) {
  __shared__ float As[64][68];
  __shared__ float BsT[64][68];
  __shared__ float tab[16];
  const int t = threadIdx.x;
  const int bk = blockIdx.x & 63;
  const int bn = blockIdx.x >> 6;
  const int n0 = bn << 6, k0 = bk << 6;
  if (t < 16) tab[t] = NF4_TAB[t];
#pragma unroll
  for (int i = 0; i < 16; ++i) {
    int idx = i * 256 + t;
    int p = idx >> 6, q = idx & 63;
    As[p][q]  = lA[(size_t)p * K_DIM + k0 + q];
    BsT[q][p] = lB[(size_t)(n0 + p) * 64 + q];
  }
  __syncthreads();
  const int tx = t & 15, ty = t >> 4;
  float acc[4][4] = {};
#pragma unroll 8
  for (int r = 0; r < 64; ++r) {
    float4 av = *(const float4*)&As[r][tx * 4];
    float4 bv = *(const float4*)&BsT[r][ty * 4];
    float aa[4] = {av.x, av.y, av.z, av.w};
    float bb[4] = {bv.x, bv.y, bv.z, bv.w};
#pragma unroll
    for (int i = 0; i < 4; ++i)
#pragma unroll
      for (int j = 0; j < 4; ++j) acc[i][j] += bb[i] * aa[j];
  }
#pragma unroll
  for (int i = 0; i < 4; ++i) {
    int row = n0 + ty * 4 + i;
    float amv = am[row * 64 + bk];
    int2 q2 = *(const int2*)&qw[(size_t)row * 2048 + (k0 >> 1) + tx * 2];
    float w0 = tab[q2.x & 15]        * amv + acc[i][0];
    float w1 = tab[(q2.x >> 4) & 15] * amv + acc[i][1];
    float w2 = tab[q2.y & 15]        * amv + acc[i][2];
    float w3 = tab[(q2.y >> 4) & 15] * amv + acc[i][3];
    ushort4 o; o.x = f2b(w0); o.y = f2b(w1); o.z = f2b(w2); o.w = f2b(w3);
    *(ushort4*)&W[(size_t)row * K_DIM + k0 + tx * 4] = o;
  }
}

// ---------------- K3: phased bf16 GEMM, C[m][n] = sum_k A[m][k]*B[n][k] -------
// BM=128, BN=256, BK=64. 512 threads = 8 waves (1M x 8N), per-wave out 128x32.
// 3 rotating LDS buffers (48KB each): stage K-tile t+2 while computing t.
// 2 phases per K-tile (qm halves of M), 16 MFMA + 12 ds_read_b128 each.
// One s_waitcnt vmcnt(6) per K-tile (counted, never 0).
#define LDSBUF 24576  // ushorts per buffer: A 128*64 + B 256*64

#define FENCE() asm volatile("" ::: "memory")
#define BAR() do { FENCE(); __builtin_amdgcn_s_barrier(); FENCE(); } while (0)

// compute one qm-half: 8 A-frag reads + 4 B-frag reads, 16 MFMA into acc[QM*4+mi][ni]
#define COMPUTE_HALF(QM, BC)                                                     \
  do {                                                                           \
    bf16x8 af[4][2], bv[2][2];                                                   \
    _Pragma("unroll") for (int mi = 0; mi < 4; ++mi) {                           \
      int row = (QM) * 64 + mi * 16 + lr;                                        \
      int rb = row * 64, x = row & 7;                                            \
      _Pragma("unroll") for (int ks = 0; ks < 2; ++ks) {                         \
        int slot = ((ks << 2) | lk) ^ x;                                         \
        af[mi][ks] = *(const bf16x8*)((BC) + rb + slot * 8);                     \
      }                                                                          \
    }                                                                            \
    _Pragma("unroll") for (int ni = 0; ni < 2; ++ni) {                           \
      int row = (wid << 5) + ni * 16 + lr;                                       \
      int rb = 8192 + row * 64, x = row & 7;                                     \
      _Pragma("unroll") for (int ks = 0; ks < 2; ++ks) {                         \
        int slot = ((ks << 2) | lk) ^ x;                                         \
        bv[ni][ks] = *(const bf16x8*)((BC) + rb + slot * 8);                     \
      }                                                                          \
    }                                                                            \
    __builtin_amdgcn_s_setprio(1);                                               \
    _Pragma("unroll") for (int ks = 0; ks < 2; ++ks)                             \
    _Pragma("unroll") for (int mi = 0; mi < 4; ++mi)                             \
    _Pragma("unroll") for (int ni = 0; ni < 2; ++ni)                             \
      acc[(QM) * 4 + mi][ni] = __builtin_amdgcn_mfma_f32_16x16x32_bf16(          \
          af[mi][ks], bv[ni][ks], acc[(QM) * 4 + mi][ni], 0, 0, 0);              \
    __builtin_amdgcn_s_setprio(0);                                               \
  } while (0)

__global__ void __launch_bounds__(512, 2) k_gemm(const unsigned short* __restrict__ A,
                                                 const unsigned short* __restrict__ B,
                                                 float* __restrict__ C) {
  __shared__ unsigned short lds[3 * LDSBUF];  // 144 KB
  const int tid = threadIdx.x;
  const int ln = tid & 63;
  const int wid = tid >> 6;  // 0..7
  const int lr = ln & 15;    // fragment row within 16
  const int lk = ln >> 4;    // k-group 0..3

  // XCD-bijective swizzle (nwg=256, 256%8==0): contiguous 32-block chunks per XCD
  const int sw = (blockIdx.x & 7) * 32 + (blockIdx.x >> 3);
  const int bm = sw & 15;    // M/128 = 16 (fast-moving: same-XCD blocks share B panels)
  const int bn = sw >> 4;    // N/256 = 16
  const size_t arow0 = (size_t)bm * 128;
  const size_t brow0 = (size_t)bn * 256;

  // one block-wide 8KB global_load_lds: 64 rows x 128B, linear LDS dest,
  // pre-swizzled global source slot (rule #21); LDS[row][s] = G[row][s ^ (row&7)]
  const int srow = (wid << 3) + (ln >> 3);  // row within 64-row chunk
  const int gs0 = (ln & 7) ^ (srow & 7);    // pre-swizzled 16B source slot
  auto stage = [&](const unsigned short* __restrict__ G, size_t grow0, int kt,
                   unsigned short* dst) {
    const char* g = (const char*)(G + (grow0 + srow) * (size_t)K_DIM) + kt * 128 + gs0 * 16;
    __builtin_amdgcn_global_load_lds(
        (const __attribute__((address_space(1))) uint32_t*)g,
        (__attribute__((address_space(3))) uint32_t*)(dst + (size_t)(wid << 3) * 64),
        16, 0, 0);
  };

  f32x4 acc[8][2] = {};

  // prologue: K-tile 0 -> buf0, K-tile 1 -> buf1 (6 loads each)
  stage(A, arow0, 0, lds);                     // A rows 0-63
  stage(A, arow0 + 64, 0, lds + 4096);         // A rows 64-127
  stage(B, brow0, 0, lds + 8192);              // B rows 0-63
  stage(B, brow0 + 64, 0, lds + 12288);
  stage(B, brow0 + 128, 0, lds + 16384);
  stage(B, brow0 + 192, 0, lds + 20480);
  {
    unsigned short* b1 = lds + LDSBUF;
    stage(A, arow0, 1, b1);
    stage(A, arow0 + 64, 1, b1 + 4096);
    stage(B, brow0, 1, b1 + 8192);
    stage(B, brow0 + 64, 1, b1 + 12288);
    stage(B, brow0 + 128, 1, b1 + 16384);
    stage(B, brow0 + 192, 1, b1 + 20480);
  }
  asm volatile("s_waitcnt vmcnt(6)" ::: "memory");  // K-tile 0 landed; K1 in flight
  BAR();

  int cb = 0, sb = 2;  // compute-buffer, stage-buffer indices
#pragma unroll 1
  for (int t = 0; t < K_DIM / 64; ++t) {
    const unsigned short* bc = lds + cb * LDSBUF;
    unsigned short* sd = lds + sb * LDSBUF;
    int kt2 = t + 2; kt2 = (kt2 >= 64) ? kt2 - 64 : kt2;  // wrap: harmless re-stage

    // ---- phase 1 (qm=0): 12 ds_reads + 3 stage issues + 16 MFMA ----
    stage(A, arow0, kt2, sd);
    stage(A, arow0 + 64, kt2, sd + 4096);
    stage(B, brow0, kt2, sd + 8192);
    COMPUTE_HALF(0, bc);
    BAR();

    // ---- phase 2 (qm=1) ----
    stage(B, brow0 + 64, kt2, sd + 12288);
    stage(B, brow0 + 128, kt2, sd + 16384);
    stage(B, brow0 + 192, kt2, sd + 20480);
    COMPUTE_HALF(1, bc);
    // counted wait: allow this iteration's 6 loads in flight; K-tile t+1 must be done
    asm volatile("s_waitcnt vmcnt(6)" ::: "memory");
    BAR();

    cb = (cb == 2) ? 0 : cb + 1;
    sb = (sb == 2) ? 0 : sb + 1;
  }

  // epilogue: C/D layout col = lane&15, row = (lane>>4)*4 + reg
  float* Cb = C + arow0 * N_DIM + brow0 + (wid << 5);
#pragma unroll
  for (int mi8 = 0; mi8 < 8; ++mi8)
#pragma unroll
    for (int ni = 0; ni < 2; ++ni)
#pragma unroll
      for (int r = 0; r < 4; ++r)
        Cb[(size_t)(mi8 * 16 + lk * 4 + r) * N_DIM + ni * 16 + lr] = acc[mi8][ni][r];
}

extern "C" void kernel_launch(void* const* d_in, const int* in_sizes, int n_in,
                              void* d_out, int out_size, void* d_ws, size_t ws_size,
                              hipStream_t stream) {
  const float* input  = (const float*)d_in[0];
  const int* qweight  = (const int*)d_in[1];
  const float* absmax = (const float*)d_in[2];
  const float* lora_A = (const float*)d_in[3];
  const float* lora_B = (const float*)d_in[4];
  float* out = (float*)d_out;

  unsigned short* A16 = (unsigned short*)d_ws;
  unsigned short* B16 = A16 + (size_t)M_DIM * K_DIM;

  int n4 = M_DIM * K_DIM / 4;
  k_cvt<<<n4 / 256, 256, 0, stream>>>((const float4*)input, (ushort4*)A16, n4);
  k_build_w<<<(N_DIM / 64) * (K_DIM / 64), 256, 0, stream>>>(qweight, absmax, lora_A,
                                                             lora_B, B16);
  k_gemm<<<256, 512, 0, stream>>>(A16, B16, out);
}

// Round 3
// 115.868 us; speedup vs baseline: 1.1429x; 1.0132x over previous
//
#include <hip/hip_runtime.h>
#include <hip/hip_bf16.h>
#include <stdint.h>

#define M_DIM 2048
#define N_DIM 4096
#define K_DIM 4096

typedef __attribute__((ext_vector_type(8))) __bf16 bf16x8;
typedef __attribute__((ext_vector_type(4))) float f32x4;

__device__ __constant__ float NF4_TAB[16] = {
    -1.0f, -0.6961928009986877f, -0.5250730514526367f, -0.39491748809814453f,
    -0.28444138169288635f, -0.18477343022823334f, -0.09105003625154495f, 0.0f,
    0.07958029955625534f, 0.16093020141124725f, 0.24611230194568634f,
    0.33791524171829224f, 0.44070982933044434f, 0.5626170039176941f,
    0.7229568362236023f, 1.0f};

// fp32 -> bf16 round-to-nearest-even
__device__ inline unsigned short f2b(float f) {
  union { float f; uint32_t u; } v; v.f = f;
  uint32_t u = v.u;
  return (unsigned short)((u + 0x7fffu + ((u >> 16) & 1u)) >> 16);
}

// ---------------- K1: input fp32 -> bf16 ----------------
__global__ void k_cvt(const float4* __restrict__ in, ushort4* __restrict__ out, int n) {
  int i = blockIdx.x * 256 + threadIdx.x;
  if (i < n) {
    float4 v = in[i];
    ushort4 o;
    o.x = f2b(v.x); o.y = f2b(v.y); o.z = f2b(v.z); o.w = f2b(v.w);
    out[i] = o;
  }
}

// ---------------- K2: fused NF4 dequant + LoRA fold -> bf16 W (N x K) ----------
__global__ void __launch_bounds__(256) k_build_w(
    const int* __restrict__ qw, const float* __restrict__ am,
    const float* __restrict__ lA, const float* __restrict__ lB,
    unsigned short* __restrict__ W) {
  __shared__ float As[64][68];
  __shared__ float BsT[64][68];
  __shared__ float tab[16];
  const int t = threadIdx.x;
  const int bk = blockIdx.x & 63;
  const int bn = blockIdx.x >> 6;
  const int n0 = bn << 6, k0 = bk << 6;
  if (t < 16) tab[t] = NF4_TAB[t];
#pragma unroll
  for (int i = 0; i < 16; ++i) {
    int idx = i * 256 + t;
    int p = idx >> 6, q = idx & 63;
    As[p][q]  = lA[(size_t)p * K_DIM + k0 + q];
    BsT[q][p] = lB[(size_t)(n0 + p) * 64 + q];
  }
  __syncthreads();
  const int tx = t & 15, ty = t >> 4;
  float acc[4][4] = {};
#pragma unroll 8
  for (int r = 0; r < 64; ++r) {
    float4 av = *(const float4*)&As[r][tx * 4];
    float4 bv = *(const float4*)&BsT[r][ty * 4];
    float aa[4] = {av.x, av.y, av.z, av.w};
    float bb[4] = {bv.x, bv.y, bv.z, bv.w};
#pragma unroll
    for (int i = 0; i < 4; ++i)
#pragma unroll
      for (int j = 0; j < 4; ++j) acc[i][j] += bb[i] * aa[j];
  }
#pragma unroll
  for (int i = 0; i < 4; ++i) {
    int row = n0 + ty * 4 + i;
    float amv = am[row * 64 + bk];
    int2 q2 = *(const int2*)&qw[(size_t)row * 2048 + (k0 >> 1) + tx * 2];
    float w0 = tab[q2.x & 15]        * amv + acc[i][0];
    float w1 = tab[(q2.x >> 4) & 15] * amv + acc[i][1];
    float w2 = tab[q2.y & 15]        * amv + acc[i][2];
    float w3 = tab[(q2.y >> 4) & 15] * amv + acc[i][3];
    ushort4 o; o.x = f2b(w0); o.y = f2b(w1); o.z = f2b(w2); o.w = f2b(w3);
    *(ushort4*)&W[(size_t)row * K_DIM + k0 + tx * 4] = o;
  }
}

// ---------------- K3: phased bf16 GEMM, C[m][n] = sum_k A[m][k]*B[n][k] -------
// BM=128, BN=256, BK=64. 512 threads = 8 waves as 2(M) x 4(N); wave tile 64x64
// (square => minimal LDS bytes/FLOP: each wave reads only its own 8KB A + 8KB B
// per K-tile; 128KB/CU/K-tile vs 192KB for the old 128x32 wave tile).
// 3 rotating LDS buffers (48KB each): stage K-tile t+2 while computing t.
// 2 phases per K-tile (ks halves of K), each {3 stage + 8 ds_read_b128 + 16 MFMA}.
// One s_waitcnt vmcnt(6) per K-tile (counted, never 0).
#define LDSBUF 24576  // ushorts per buffer: A 128*64 + B 256*64

#define FENCE() asm volatile("" ::: "memory")
#define BAR() do { FENCE(); __builtin_amdgcn_s_barrier(); FENCE(); } while (0)

// one K-half phase: 4 A-frag + 4 B-frag reads (XOR-swizzled), 16 MFMA
#define COMPUTE_PHASE(KS, BC)                                                    \
  do {                                                                           \
    bf16x8 af[4], bv[4];                                                         \
    _Pragma("unroll") for (int mi = 0; mi < 4; ++mi) {                           \
      int row = wr * 64 + mi * 16 + lr;                                          \
      int slot = (((KS) << 2) | lk) ^ (row & 7);                                 \
      af[mi] = *(const bf16x8*)((BC) + row * 64 + slot * 8);                     \
    }                                                                            \
    _Pragma("unroll") for (int ni = 0; ni < 4; ++ni) {                           \
      int row = wc * 64 + ni * 16 + lr;                                          \
      int slot = (((KS) << 2) | lk) ^ (row & 7);                                 \
      bv[ni] = *(const bf16x8*)((BC) + 8192 + row * 64 + slot * 8);              \
    }                                                                            \
    __builtin_amdgcn_s_setprio(1);                                               \
    _Pragma("unroll") for (int mi = 0; mi < 4; ++mi)                             \
    _Pragma("unroll") for (int ni = 0; ni < 4; ++ni)                             \
      acc[mi][ni] = __builtin_amdgcn_mfma_f32_16x16x32_bf16(                     \
          af[mi], bv[ni], acc[mi][ni], 0, 0, 0);                                 \
    __builtin_amdgcn_s_setprio(0);                                               \
  } while (0)

__global__ void __launch_bounds__(512, 2) k_gemm(const unsigned short* __restrict__ A,
                                                 const unsigned short* __restrict__ B,
                                                 float* __restrict__ C) {
  __shared__ unsigned short lds[3 * LDSBUF];  // 144 KB
  const int tid = threadIdx.x;
  const int ln = tid & 63;
  const int wid = tid >> 6;  // 0..7
  const int wr = wid >> 2;   // 0..1  (M)
  const int wc = wid & 3;    // 0..3  (N)
  const int lr = ln & 15;    // fragment row within 16
  const int lk = ln >> 4;    // k-group 0..3

  // XCD-bijective swizzle (nwg=256, 256%8==0): contiguous 32-block chunks per XCD
  const int sw = (blockIdx.x & 7) * 32 + (blockIdx.x >> 3);
  const int bm = sw & 15;    // M/128 = 16 (fast-moving: same-XCD blocks share B panels)
  const int bn = sw >> 4;    // N/256 = 16
  const size_t arow0 = (size_t)bm * 128;
  const size_t brow0 = (size_t)bn * 256;

  // one block-wide 8KB global_load_lds: 64 rows x 128B, linear LDS dest,
  // pre-swizzled global source slot (rule #21); LDS[row][s] = G[row][s ^ (row&7)]
  const int srow = (wid << 3) + (ln >> 3);  // row within 64-row chunk
  const int gs0 = (ln & 7) ^ (srow & 7);    // pre-swizzled 16B source slot
  auto stage = [&](const unsigned short* __restrict__ G, size_t grow0, int kt,
                   unsigned short* dst) {
    const char* g = (const char*)(G + (grow0 + srow) * (size_t)K_DIM) + kt * 128 + gs0 * 16;
    __builtin_amdgcn_global_load_lds(
        (const __attribute__((address_space(1))) uint32_t*)g,
        (__attribute__((address_space(3))) uint32_t*)(dst + (size_t)(wid << 3) * 64),
        16, 0, 0);
  };

  f32x4 acc[4][4] = {};

  // prologue: K-tile 0 -> buf0, K-tile 1 -> buf1 (6 loads each)
  stage(A, arow0, 0, lds);                     // A rows 0-63
  stage(A, arow0 + 64, 0, lds + 4096);         // A rows 64-127
  stage(B, brow0, 0, lds + 8192);              // B rows 0-63
  stage(B, brow0 + 64, 0, lds + 12288);
  stage(B, brow0 + 128, 0, lds + 16384);
  stage(B, brow0 + 192, 0, lds + 20480);
  {
    unsigned short* b1 = lds + LDSBUF;
    stage(A, arow0, 1, b1);
    stage(A, arow0 + 64, 1, b1 + 4096);
    stage(B, brow0, 1, b1 + 8192);
    stage(B, brow0 + 64, 1, b1 + 12288);
    stage(B, brow0 + 128, 1, b1 + 16384);
    stage(B, brow0 + 192, 1, b1 + 20480);
  }
  asm volatile("s_waitcnt vmcnt(6)" ::: "memory");  // K-tile 0 landed; K1 in flight
  BAR();

  int cb = 0, sb = 2;  // compute-buffer, stage-buffer indices
#pragma unroll 1
  for (int t = 0; t < K_DIM / 64; ++t) {
    const unsigned short* bc = lds + cb * LDSBUF;
    unsigned short* sd = lds + sb * LDSBUF;
    int kt2 = t + 2; kt2 = (kt2 >= 64) ? kt2 - 64 : kt2;  // wrap: harmless re-stage

    // ---- phase 1 (ks=0): 3 stage issues + 8 ds_reads + 16 MFMA ----
    stage(A, arow0, kt2, sd);
    stage(A, arow0 + 64, kt2, sd + 4096);
    stage(B, brow0, kt2, sd + 8192);
    COMPUTE_PHASE(0, bc);
    BAR();

    // ---- phase 2 (ks=1) ----
    stage(B, brow0 + 64, kt2, sd + 12288);
    stage(B, brow0 + 128, kt2, sd + 16384);
    stage(B, brow0 + 192, kt2, sd + 20480);
    COMPUTE_PHASE(1, bc);
    // counted wait: allow this iteration's 6 loads in flight; K-tile t+1 must be done
    asm volatile("s_waitcnt vmcnt(6)" ::: "memory");
    BAR();

    cb = (cb == 2) ? 0 : cb + 1;
    sb = (sb == 2) ? 0 : sb + 1;
  }

  // epilogue: C/D layout col = lane&15, row = (lane>>4)*4 + reg
  float* Cb = C + (arow0 + (size_t)wr * 64) * N_DIM + brow0 + wc * 64;
#pragma unroll
  for (int mi = 0; mi < 4; ++mi)
#pragma unroll
    for (int ni = 0; ni < 4; ++ni)
#pragma unroll
      for (int r = 0; r < 4; ++r)
        Cb[(size_t)(mi * 16 + lk * 4 + r) * N_DIM + ni * 16 + lr] = acc[mi][ni][r];
}

extern "C" void kernel_launch(void* const* d_in, const int* in_sizes, int n_in,
                              void* d_out, int out_size, void* d_ws, size_t ws_size,
                              hipStream_t stream) {
  const float* input  = (const float*)d_in[0];
  const int* qweight  = (const int*)d_in[1];
  const float* absmax = (const float*)d_in[2];
  const float* lora_A = (const float*)d_in[3];
  const float* lora_B = (const float*)d_in[4];
  float* out = (float*)d_out;

  unsigned short* A16 = (unsigned short*)d_ws;
  unsigned short* B16 = A16 + (size_t)M_DIM * K_DIM;

  int n4 = M_DIM * K_DIM / 4;
  k_cvt<<<n4 / 256, 256, 0, stream>>>((const float4*)input, (ushort4*)A16, n4);
  k_build_w<<<(N_DIM / 64) * (K_DIM / 64), 256, 0, stream>>>(qweight, absmax, lora_A,
                                                             lora_B, B16);
  k_gemm<<<256, 512, 0, stream>>>(A16, B16, out);
}